// Round 2
// baseline (266.791 us; speedup 1.0000x reference)
//
#include <hip/hip_runtime.h>

// Problem constants (from reference): B=8, L=4096, D=1024, G=128, d=8
#define PB 8
#define PL 4096
#define PD 1024
#define PG 128
#define SEG 32
#define NSEG (PL / SEG)          // 128
#define NEPS 1e-5f

// d_out layout (flat float32): [y: B*L*D][count: B][mean: B*G][var: B*G]
#define YSZ ((size_t)PB * PL * PD)
#define COUNT_OFF (YSZ)
#define MEAN_OFF (YSZ + PB)
#define VAR_OFF (YSZ + PB + (size_t)PB * PG)

// Native 4-float vector for __builtin_nontemporal_store (HIP float4 is a
// class type the builtin rejects).
typedef float vf4 __attribute__((ext_vector_type(4)));

// State is raw moments per (b,g): n = #elements, S = sum(x), Q = sum(x^2).
// Merge is pure addition (commutative/associative) -> no divide in any
// loop-carried chain. mean = S/n, var = Q/n - mean^2.

// Kernel 1: per-(b, seg, g) aggregate of SEG steps. Block = 256 threads =
// 128 groups x 2 halves; thread u loads float4 at row*1024 + u*4 so the
// block reads one contiguous 4KB step per t. No ordering constraints ->
// deep unroll, loads fully independent.
__global__ __launch_bounds__(256) void k_agg(const float* __restrict__ x,
                                             const int* __restrict__ mask,
                                             float* __restrict__ aggN,
                                             float* __restrict__ aggS,
                                             float* __restrict__ aggQ) {
    int blk = blockIdx.x;
    int b = blk >> 7;              // / NSEG
    int seg = blk & (NSEG - 1);
    int u = threadIdx.x;
    size_t row0 = (size_t)b * PL + (size_t)seg * SEG;
    const float4* xp = (const float4*)x + row0 * (PD / 4) + u;
    const int* mp = mask + b * PL + seg * SEG;

    float S = 0.f, Q = 0.f, Sb = 0.f, Qb = 0.f, nc = 0.f;
#pragma unroll 8
    for (int t = 0; t < SEG; t += 2) {
        float4 v0 = xp[(size_t)t * (PD / 4)];
        float4 v1 = xp[(size_t)(t + 1) * (PD / 4)];
        float f0 = (float)mp[t];
        float f1 = (float)mp[t + 1];
        nc += f0 + f1;
        S  = fmaf(f0, v0.x + v0.y + v0.z + v0.w, S);
        Q  = fmaf(f0, fmaf(v0.x, v0.x, fmaf(v0.y, v0.y, fmaf(v0.z, v0.z, v0.w * v0.w))), Q);
        Sb = fmaf(f1, v1.x + v1.y + v1.z + v1.w, Sb);
        Qb = fmaf(f1, fmaf(v1.x, v1.x, fmaf(v1.y, v1.y, fmaf(v1.z, v1.z, v1.w * v1.w))), Qb);
    }
    S += Sb; Q += Qb;
    S += __shfl_xor(S, 1);
    Q += __shfl_xor(Q, 1);
    if ((u & 1) == 0) {
        int idx = (b * NSEG + seg) * PG + (u >> 1);
        aggN[idx] = 8.0f * nc;
        aggS[idx] = S;
        aggQ[idx] = Q;
    }
}

// Kernel 2: hierarchical (parallel) exclusive prefix over NSEG segment
// aggregates per (b,g). 8 threads per (b,g) pair; each thread batch-loads
// its 16-segment chunk (all loads independent -> one latency round trip),
// computes a local prefix, and a 3-step __shfl_up scan across the 8-lane
// subgroup provides the chunk offsets. Replaces the previous 128-deep
// serial pointer-walk (~25-30us of L3 latency at 4-block occupancy).
// Also writes final count/mean/var outputs.
__global__ __launch_bounds__(256) void k_scan(const void* __restrict__ prev_count,
                                              const float* __restrict__ prev_mean,
                                              const float* __restrict__ prev_var,
                                              const float* __restrict__ aggN,
                                              const float* __restrict__ aggS,
                                              const float* __restrict__ aggQ,
                                              float* __restrict__ carN,
                                              float* __restrict__ carS,
                                              float* __restrict__ carQ,
                                              float* __restrict__ out) {
    const int CH = NSEG / 8;                   // 16 segments per thread
    int t = blockIdx.x * 256 + threadIdx.x;    // 8192 threads total
    int pair = t >> 3;                         // (b,g) index, 0..1023
    int c = t & 7;                             // chunk index within pair
    int b = pair >> 7;
    int idx0 = b * NSEG * PG + (c * CH) * PG + (pair & (PG - 1));

    // Batch-load the whole chunk: 48 independent loads in flight.
    float an[CH], aS[CH], aQ[CH];
#pragma unroll
    for (int i = 0; i < CH; ++i) {
        an[i] = aggN[idx0 + i * PG];
        aS[i] = aggS[idx0 + i * PG];
        aQ[i] = aggQ[idx0 + i * PG];
    }
    float ln = 0.f, lS = 0.f, lQ = 0.f;
#pragma unroll
    for (int i = 0; i < CH; ++i) { ln += an[i]; lS += aS[i]; lQ += aQ[i]; }

    // Inclusive scan of chunk sums across the 8-lane subgroup.
    float sn = ln, sS = lS, sQ = lQ;
    int lane = threadIdx.x & 63;
#pragma unroll
    for (int d = 1; d < 8; d <<= 1) {
        float tn = __shfl_up(sn, d);
        float tS = __shfl_up(sS, d);
        float tQ = __shfl_up(sQ, d);
        if ((lane & 7) >= d) { sn += tn; sS += tS; sQ += tQ; }
    }

    // Base moments from prev state. prev_count is int64 per reference;
    // int32 fallback heuristic (kept identical to verified kernel).
    const long long* p64 = (const long long*)prev_count;
    const int* p32 = (const int*)prev_count;
    long long pv = p64[b];
    float cnt = (pv >= 0 && pv < (1LL << 31)) ? (float)pv : (float)p32[b];
    float n0 = 8.0f * cnt;
    float m0 = prev_mean[pair];
    float S0 = m0 * n0;
    float Q0 = fmaf(m0, m0, prev_var[pair]) * n0;   // (var + mean^2) * n

    // Exclusive offset for this chunk = base + (inclusive - local).
    float rn = n0 + (sn - ln);
    float rS = S0 + (sS - lS);
    float rQ = Q0 + (sQ - lQ);
#pragma unroll
    for (int i = 0; i < CH; ++i) {
        carN[idx0 + i * PG] = rn;
        carS[idx0 + i * PG] = rS;
        carQ[idx0 + i * PG] = rQ;
        rn += an[i]; rS += aS[i]; rQ += aQ[i];
    }
    if (c == 7) {   // lane holding the full total
        float inv = 1.0f / rn;
        float mean = rS * inv;
        out[MEAN_OFF + pair] = mean;
        out[VAR_OFF + pair] = fmaf(-mean, mean, rQ * inv);
        if ((pair & (PG - 1)) == 0) out[COUNT_OFF + b] = rn * 0.125f; // exact: n = 8*count
    }
}

// Kernel 3: per-(b, seg) ordered walk of SEG steps from the carry. Carried
// chain is 3 independent FMAs; normalization math (rcp/rsq) is off-chain.
// Prefetch depth 2 (was 1) to cover HBM-miss latency at 4 waves/SIMD; y
// stores are non-temporal (y is never re-read; don't evict x from L2/L3).
__global__ __launch_bounds__(256) void k_out(const float* __restrict__ x,
                                             const int* __restrict__ mask,
                                             const float* __restrict__ weight,
                                             const float* __restrict__ bias,
                                             const float* __restrict__ carN,
                                             const float* __restrict__ carS,
                                             const float* __restrict__ carQ,
                                             float* __restrict__ out) {
    int blk = blockIdx.x;
    int b = blk >> 7;
    int seg = blk & (NSEG - 1);
    int u = threadIdx.x;
    int g = u >> 1;

    int cidx = (b * NSEG + seg) * PG + g;
    float n = carN[cidx];
    float S = carS[cidx];
    float Q = carQ[cidx];

    size_t row0 = (size_t)b * PL + (size_t)seg * SEG;
    const float4* xp = (const float4*)x + row0 * (PD / 4) + u;
    vf4* yp = (vf4*)out + row0 * (PD / 4) + u;
    const int* mp = mask + b * PL + seg * SEG;

    float4 w4 = ((const float4*)weight)[u];
    float4 b4 = ((const float4*)bias)[u];
    float gx = w4.x + 1.0f, gy = w4.y + 1.0f, gz = w4.z + 1.0f, gw = w4.w + 1.0f;

    float4 v0 = xp[0];
    float4 v1 = xp[PD / 4];
#pragma unroll 4
    for (int t = 0; t < SEG; ++t) {
        int tn = (t + 2 < SEG) ? (t + 2) : (SEG - 1);
        float4 vn = xp[(size_t)tn * (PD / 4)];
        float f = (float)mp[t];
        float s  = v0.x + v0.y + v0.z + v0.w;
        float ss = fmaf(v0.x, v0.x, fmaf(v0.y, v0.y, fmaf(v0.z, v0.z, v0.w * v0.w)));
        s  += __shfl_xor(s, 1);
        ss += __shfl_xor(ss, 1);
        n = fmaf(f, 8.0f, n);
        S = fmaf(f, s, S);
        Q = fmaf(f, ss, Q);
        float inv  = __builtin_amdgcn_rcpf(n);
        float mean = S * inv;
        float var  = fmaf(-mean, mean, Q * inv);
        float rstd = __builtin_amdgcn_rsqf(var + NEPS);
        vf4 y;
        y.x = fmaf((v0.x - mean) * rstd, gx, b4.x);
        y.y = fmaf((v0.y - mean) * rstd, gy, b4.y);
        y.z = fmaf((v0.z - mean) * rstd, gz, b4.z);
        y.w = fmaf((v0.w - mean) * rstd, gw, b4.w);
        __builtin_nontemporal_store(y, yp + (size_t)t * (PD / 4));
        v0 = v1; v1 = vn;
    }
}

extern "C" void kernel_launch(void* const* d_in, const int* in_sizes, int n_in,
                              void* d_out, int out_size, void* d_ws, size_t ws_size,
                              hipStream_t stream) {
    const float* x          = (const float*)d_in[0];
    const void*  prev_count = d_in[1];
    const float* prev_mean  = (const float*)d_in[2];
    const float* prev_var   = (const float*)d_in[3];
    const float* weight     = (const float*)d_in[4];
    const float* bias       = (const float*)d_in[5];
    const int*   mask       = (const int*)d_in[6];
    float* out = (float*)d_out;
    float* ws  = (float*)d_ws;

    const size_t A = (size_t)PB * NSEG * PG;   // 131072 floats per array
    float* aggN = ws + 0 * A;
    float* aggS = ws + 1 * A;
    float* aggQ = ws + 2 * A;
    float* carN = ws + 3 * A;
    float* carS = ws + 4 * A;
    float* carQ = ws + 5 * A;   // 3 MiB of workspace total

    hipLaunchKernelGGL(k_agg, dim3(PB * NSEG), dim3(256), 0, stream,
                       x, mask, aggN, aggS, aggQ);
    hipLaunchKernelGGL(k_scan, dim3((PB * PG * 8) / 256), dim3(256), 0, stream,
                       prev_count, prev_mean, prev_var,
                       aggN, aggS, aggQ, carN, carS, carQ, out);
    hipLaunchKernelGGL(k_out, dim3(PB * NSEG), dim3(256), 0, stream,
                       x, mask, weight, bias, carN, carS, carQ, out);
}